// Round 1
// baseline (605.547 us; speedup 1.0000x reference)
//
#include <hip/hip_runtime.h>
#include <stdint.h>

// ---------------------------------------------------------------------------
// FourierLayer: 5x [conv2x2s2 + BN(eval) + ReLU] -> fuse proj -> rFFT(32) ->
// gating (top-3 softmax) on MI355X.
//
// Conv_k = GEMM: C[M x 256] = A[M x 1024] * B^T, with intermediates stored in
// "patch-Z" layout so each layer's A is a dense row-major matrix:
//   addr(n,y,x,co) = n*(h*w*256) + (y>>1)*(w/2)*1024 + (x>>1)*1024
//                    + ((y&1)*2+(x&1))*256 + co
// => next layer's row r = (n, y>>1, x>>1), k = q*256+ci is A[r*1024 + k].
// ---------------------------------------------------------------------------

typedef __attribute__((ext_vector_type(8))) short bf16x8;
typedef __attribute__((ext_vector_type(4))) float f32x4;

#define DEV __device__ __forceinline__
#define GLOBAL_AS __attribute__((address_space(1)))
#define LDS_AS __attribute__((address_space(3)))

DEV unsigned short f2bf(float f) {
  union { float f; uint32_t u; } v; v.f = f;
  uint32_t u = v.u;
  return (unsigned short)((u + 0x7fffu + ((u >> 16) & 1u)) >> 16);
}

DEV void async16(const void* g, void* l) {
  __builtin_amdgcn_global_load_lds((GLOBAL_AS void*)g, (LDS_AS void*)l, 16, 0, 0);
}

// --------------------------- weight prep ----------------------------------
// Bt_all[l][co][q*256+ci] = conv_w[l][co][ci][dy][dx] * gamma/sqrt(var+eps)
// bias_all[l][co] = (conv_b - mean)*scale + beta ; Bt_fuse = bf16(fuse_w)
__global__ void prep_kernel(const float* __restrict__ conv_w,
                            const float* __restrict__ conv_b,
                            const float* __restrict__ gamma,
                            const float* __restrict__ beta,
                            const float* __restrict__ mean,
                            const float* __restrict__ var,
                            const float* __restrict__ fuse_w,
                            unsigned short* __restrict__ Bt_all,
                            unsigned short* __restrict__ Bt_fuse,
                            float* __restrict__ bias_all) {
  int idx = blockIdx.x * 256 + threadIdx.x;
  const int NB = 5 * 256 * 1024;
  if (idx < NB) {
    int l = idx >> 18;
    int rem = idx & 262143;
    int co = rem >> 10;
    int k = rem & 1023;
    int q = k >> 8;
    int ci = k & 255;
    int lc = l * 256 + co;
    float scale = gamma[lc] * rsqrtf(var[lc] + 1e-5f);
    float w = conv_w[(((size_t)lc * 256 + ci) << 2) + q] * scale;
    Bt_all[idx] = f2bf(w);
  } else if (idx < NB + 65536) {
    int i = idx - NB;
    Bt_fuse[i] = f2bf(fuse_w[i]);
  } else if (idx < NB + 65536 + 1280) {
    int j = idx - (NB + 65536);
    float scale = gamma[j] * rsqrtf(var[j] + 1e-5f);
    bias_all[j] = (conv_b[j] - mean[j]) * scale + beta[j];
  }
}

// --------------------------- generic GEMM ----------------------------------
// C[M x 256] = A[M x K](bf16, dense) * Bt[256 x K]^T + bias, optional ReLU.
// 128x128 tile, BK=64, 256 threads (2x2 waves of 64x64), 16x16x32 bf16 MFMA.
// XOR-8 swizzle on 16B units inside each 128B LDS row.
template <bool OUT_F32, bool RELU>
__global__ __launch_bounds__(256) void gemm_kernel(
    const unsigned short* __restrict__ A, const unsigned short* __restrict__ Bt,
    const float* __restrict__ bias, void* __restrict__ Out, int K,
    int hw_shift, int wsh, int hw1) {
  __shared__ __align__(16) unsigned short As[128 * 64];
  __shared__ __align__(16) unsigned short Bs[128 * 64];
  const int t = threadIdx.x;
  const int lane = t & 63, wave = t >> 6;
  const int R0 = blockIdx.y * 128, C0 = blockIdx.x * 128;
  const int wrow = (wave >> 1) * 64, wcol = (wave & 1) * 64;
  const int m16 = lane & 15, quad = lane >> 4;

  const unsigned short* ga[4];
  const unsigned short* gb[4];
#pragma unroll
  for (int p = 0; p < 4; ++p) {
    int g = p * 256 + t;
    int r = g >> 3, u = g & 7;
    int sw = (u ^ (r & 7)) << 3;
    ga[p] = A + (size_t)(R0 + r) * K + sw;
    gb[p] = Bt + (size_t)(C0 + r) * K + sw;
  }

  const f32x4 zero = {0.f, 0.f, 0.f, 0.f};
  f32x4 acc[4][4];
#pragma unroll
  for (int i = 0; i < 4; ++i)
#pragma unroll
    for (int j = 0; j < 4; ++j) acc[i][j] = zero;

  const int kIters = K >> 6;
  for (int kt = 0; kt < kIters; ++kt) {
#pragma unroll
    for (int p = 0; p < 4; ++p) {
      async16(ga[p], &As[(p * 4 + wave) * 512]);
      async16(gb[p], &Bs[(p * 4 + wave) * 512]);
      ga[p] += 64;
      gb[p] += 64;
    }
    __syncthreads();
#pragma unroll
    for (int ks = 0; ks < 2; ++ks) {
      bf16x8 af[4], bfr[4];
      int ul = (ks << 2) + quad;
#pragma unroll
      for (int f = 0; f < 4; ++f) {
        int ra = wrow + f * 16 + m16;
        af[f] = *(const bf16x8*)&As[ra * 64 + ((ul ^ (ra & 7)) << 3)];
        int rb = wcol + f * 16 + m16;
        bfr[f] = *(const bf16x8*)&Bs[rb * 64 + ((ul ^ (rb & 7)) << 3)];
      }
#pragma unroll
      for (int fi = 0; fi < 4; ++fi)
#pragma unroll
        for (int fj = 0; fj < 4; ++fj)
          acc[fi][fj] = __builtin_amdgcn_mfma_f32_16x16x32_bf16(
              af[fi], bfr[fj], acc[fi][fj], 0, 0, 0);
    }
    __syncthreads();
  }

  float biasv[4];
#pragma unroll
  for (int fj = 0; fj < 4; ++fj) biasv[fj] = bias[C0 + wcol + fj * 16 + m16];

#pragma unroll
  for (int fi = 0; fi < 4; ++fi) {
#pragma unroll
    for (int fj = 0; fj < 4; ++fj) {
      int col = C0 + wcol + fj * 16 + m16;
      f32x4 v = acc[fi][fj];
#pragma unroll
      for (int i = 0; i < 4; ++i) {
        int R = R0 + wrow + fi * 16 + quad * 4 + i;
        float val = v[i] + biasv[fj];
        if (RELU) val = fmaxf(val, 0.f);
        size_t addr;
        if (hw1) {
          addr = ((size_t)R << 8) + col;
        } else {
          int n = R >> hw_shift;
          int rem = R & ((1 << hw_shift) - 1);
          int y = rem >> wsh;
          int x = rem & ((1 << wsh) - 1);
          int q = ((y & 1) << 1) | (x & 1);
          addr = ((size_t)n << (hw_shift + 8)) + ((size_t)(y >> 1) << (wsh + 9)) +
                 ((size_t)(x >> 1) << 10) + (q << 8) + col;
        }
        if (OUT_F32)
          ((float*)Out)[addr] = val;
        else
          ((unsigned short*)Out)[addr] = f2bf(val);
      }
    }
  }
}

// --------------------------- layer 0 ---------------------------------------
// A gathered on the fly from NCHW fp32 input x (the JAX reshape is a pure
// reinterpretation: x_flat[n*262144 + ci*1024 + Y*32 + X]).
// Tile: n = blockIdx.y>>1, y0 = (blockIdx.y&1)*8; tile row r = yl*16 + x.
// K-tile kt: q = kt>>2 (dy,dx), ci0 = (kt&3)*64.
__global__ __launch_bounds__(256) void layer0_kernel(
    const float* __restrict__ X, const unsigned short* __restrict__ Bt,
    const float* __restrict__ bias, unsigned short* __restrict__ Out) {
  __shared__ __align__(16) unsigned short As[128 * 64];
  __shared__ __align__(16) unsigned short Bs[128 * 64];
  const int t = threadIdx.x;
  const int lane = t & 63, wave = t >> 6;
  const int C0 = blockIdx.x * 128;
  const int bm = blockIdx.y;
  const int n = bm >> 1, y0 = (bm & 1) * 8;
  const int wrow = (wave >> 1) * 64, wcol = (wave & 1) * 64;
  const int m16 = lane & 15, quad = lane >> 4;
  const int c3 = lane >> 3, xp = lane & 7;
  const float* xbase = X + (size_t)n * 262144;

  const unsigned short* gb[4];
#pragma unroll
  for (int p = 0; p < 4; ++p) {
    int g = p * 256 + t;
    int r = g >> 3, u = g & 7;
    gb[p] = Bt + (size_t)(C0 + r) * 1024 + ((u ^ (r & 7)) << 3);
  }

  const f32x4 zero = {0.f, 0.f, 0.f, 0.f};
  f32x4 acc[4][4];
#pragma unroll
  for (int i = 0; i < 4; ++i)
#pragma unroll
    for (int j = 0; j < 4; ++j) acc[i][j] = zero;

  for (int kt = 0; kt < 16; ++kt) {
    int q = kt >> 2, ci0 = (kt & 3) << 6;
    int dy = q >> 1, dx = q & 1;
    // A stage: each thread 16 float4 loads -> 32 bf16 scattered LDS writes
#pragma unroll
    for (int j = 0; j < 16; ++j) {
      int yl = j & 7, chi = j >> 3;
      int cil = wave * 16 + chi * 8 + c3;
      const float4 f = *(const float4*)(xbase + (size_t)(ci0 + cil) * 1024 +
                                        (2 * (y0 + yl) + dy) * 32 + xp * 4);
      float v1 = dx ? f.y : f.x;
      float v2 = dx ? f.w : f.z;
      int r1 = yl * 16 + xp * 2;
      int r2 = r1 + 1;
      int u = cil >> 3, b = cil & 7;
      As[r1 * 64 + ((u ^ (r1 & 7)) << 3) + b] = f2bf(v1);
      As[r2 * 64 + ((u ^ (r2 & 7)) << 3) + b] = f2bf(v2);
    }
#pragma unroll
    for (int p = 0; p < 4; ++p) {
      async16(gb[p], &Bs[(p * 4 + wave) * 512]);
      gb[p] += 64;
    }
    __syncthreads();
#pragma unroll
    for (int ks = 0; ks < 2; ++ks) {
      bf16x8 af[4], bfr[4];
      int ul = (ks << 2) + quad;
#pragma unroll
      for (int f = 0; f < 4; ++f) {
        int ra = wrow + f * 16 + m16;
        af[f] = *(const bf16x8*)&As[ra * 64 + ((ul ^ (ra & 7)) << 3)];
        int rb = wcol + f * 16 + m16;
        bfr[f] = *(const bf16x8*)&Bs[rb * 64 + ((ul ^ (rb & 7)) << 3)];
      }
#pragma unroll
      for (int fi = 0; fi < 4; ++fi)
#pragma unroll
        for (int fj = 0; fj < 4; ++fj)
          acc[fi][fj] = __builtin_amdgcn_mfma_f32_16x16x32_bf16(
              af[fi], bfr[fj], acc[fi][fj], 0, 0, 0);
    }
    __syncthreads();
  }

  float biasv[4];
#pragma unroll
  for (int fj = 0; fj < 4; ++fj) biasv[fj] = bias[C0 + wcol + fj * 16 + m16];

#pragma unroll
  for (int fi = 0; fi < 4; ++fi) {
#pragma unroll
    for (int fj = 0; fj < 4; ++fj) {
      int col = C0 + wcol + fj * 16 + m16;
      f32x4 v = acc[fi][fj];
#pragma unroll
      for (int i = 0; i < 4; ++i) {
        int rt = wrow + fi * 16 + quad * 4 + i;
        int y = y0 + (rt >> 4);
        int x = rt & 15;
        float val = fmaxf(v[i] + biasv[fj], 0.f);
        size_t addr = ((size_t)n << 16) + ((size_t)(y >> 1) << 13) +
                      ((size_t)(x >> 1) << 10) +
                      ((((y & 1) << 1) | (x & 1)) << 8) + col;
        Out[addr] = f2bf(val);
      }
    }
  }
}

// --------------------------- FFT + gate logits ------------------------------
// One block per b; thread d in [0,256). 32-pt real DFT (ortho), drop DC,
// amp @ w_gate, mean over d via shuffle+LDS reduce -> weights[b][9].
__global__ void fft_gate_kernel(const float* __restrict__ hbuf,
                                const float* __restrict__ w_gate,
                                float* __restrict__ weights) {
  __shared__ float cs[32], sn[32];
  __shared__ float wg[144];
  __shared__ float red[4][9];
  const int b = blockIdx.x, t = threadIdx.x;
  if (t < 32) {
    float ang = 6.283185307179586f * (float)t / 32.0f;
    cs[t] = cosf(ang);
    sn[t] = sinf(ang);
  }
  if (t < 144) wg[t] = w_gate[t];
  __syncthreads();

  float hl[32];
#pragma unroll
  for (int tt = 0; tt < 32; ++tt) hl[tt] = hbuf[(size_t)(b * 32 + tt) * 256 + t];

  float lg[9];
#pragma unroll
  for (int s = 0; s < 9; ++s) lg[s] = 0.f;

#pragma unroll
  for (int f = 1; f <= 16; ++f) {
    float re = 0.f, im = 0.f;
#pragma unroll
    for (int tt = 0; tt < 32; ++tt) {
      int idx = (f * tt) & 31;
      re += hl[tt] * cs[idx];
      im += hl[tt] * sn[idx];
    }
    float amp = sqrtf(re * re + im * im) * 0.17677669529663687f;  // 1/sqrt(32)
#pragma unroll
    for (int s = 0; s < 9; ++s) lg[s] += amp * wg[(f - 1) * 9 + s];
  }

  const int lane = t & 63, wave = t >> 6;
#pragma unroll
  for (int s = 0; s < 9; ++s) {
    float v = lg[s];
    v += __shfl_down(v, 32, 64);
    v += __shfl_down(v, 16, 64);
    v += __shfl_down(v, 8, 64);
    v += __shfl_down(v, 4, 64);
    v += __shfl_down(v, 2, 64);
    v += __shfl_down(v, 1, 64);
    if (lane == 0) red[wave][s] = v;
  }
  __syncthreads();
  if (t < 9) {
    float total = red[0][t] + red[1][t] + red[2][t] + red[3][t];
    weights[b * 9 + t] = total * (1.0f / 256.0f);
  }
}

// --------------------------- finalize: top-k gates + load -------------------
__global__ void finalize_kernel(const float* __restrict__ weights,
                                float* __restrict__ out) {
  const int t = threadIdx.x;
  if (t < 8) {
    float w[9];
    int idx[9];
#pragma unroll
    for (int s = 0; s < 9; ++s) {
      w[s] = weights[t * 9 + s];
      idx[s] = s;
    }
    // partial selection sort, descending, stable (strict >) -> matches top_k
    for (int a = 0; a < 4; ++a) {
      int best = a;
      for (int c = a + 1; c < 9; ++c)
        if (w[idx[c]] > w[idx[best]]) best = c;
      int tmp = idx[a];
      idx[a] = idx[best];
      idx[best] = tmp;
    }
    float m = w[idx[0]];
    float e0 = expf(w[idx[0]] - m);
    float e1 = expf(w[idx[1]] - m);
    float e2 = expf(w[idx[2]] - m);
    float inv = 1.0f / (e0 + e1 + e2);
    float g[9];
#pragma unroll
    for (int s = 0; s < 9; ++s) g[s] = 0.f;
    g[idx[0]] = e0 * inv;
    g[idx[1]] = e1 * inv;
    g[idx[2]] = e2 * inv;
#pragma unroll
    for (int s = 0; s < 9; ++s) out[t * 9 + s] = g[s];
  }
  __syncthreads();
  if (t < 9) {
    int cnt = 0;
#pragma unroll
    for (int b = 0; b < 8; ++b) cnt += (out[b * 9 + t] > 0.f) ? 1 : 0;
    out[72 + t] = (float)cnt;
  }
}

// --------------------------- launch ----------------------------------------
extern "C" void kernel_launch(void* const* d_in, const int* in_sizes, int n_in,
                              void* d_out, int out_size, void* d_ws,
                              size_t ws_size, hipStream_t stream) {
  (void)in_sizes; (void)n_in; (void)out_size; (void)ws_size;
  const float* x      = (const float*)d_in[0];
  const float* conv_w = (const float*)d_in[1];
  const float* conv_b = (const float*)d_in[2];
  const float* gamma  = (const float*)d_in[3];
  const float* beta   = (const float*)d_in[4];
  const float* mean   = (const float*)d_in[5];
  const float* var    = (const float*)d_in[6];
  const float* fuse_w = (const float*)d_in[7];
  const float* fuse_b = (const float*)d_in[8];
  const float* w_gate = (const float*)d_in[9];

  char* ws = (char*)d_ws;
  size_t off = 0;
  auto alloc = [&](size_t bytes) {
    void* p = ws + off;
    off = (off + bytes + 255) & ~(size_t)255;
    return p;
  };
  unsigned short* Bt_all  = (unsigned short*)alloc((size_t)5 * 262144 * 2);
  unsigned short* Bt_fuse = (unsigned short*)alloc((size_t)65536 * 2);
  float* bias_all         = (float*)alloc(1280 * 4);
  unsigned short* inter0  = (unsigned short*)alloc((size_t)65536 * 256 * 2);
  unsigned short* inter1  = (unsigned short*)alloc((size_t)16384 * 256 * 2);
  unsigned short* inter2  = (unsigned short*)alloc((size_t)4096 * 256 * 2);
  unsigned short* inter3  = (unsigned short*)alloc((size_t)1024 * 256 * 2);
  unsigned short* inter4  = (unsigned short*)alloc((size_t)256 * 256 * 2);
  float* hbuf             = (float*)alloc((size_t)256 * 256 * 4);
  float* wts              = (float*)alloc(72 * 4);

  prep_kernel<<<5381, 256, 0, stream>>>(conv_w, conv_b, gamma, beta, mean, var,
                                        fuse_w, Bt_all, Bt_fuse, bias_all);
  layer0_kernel<<<dim3(2, 512), 256, 0, stream>>>(x, Bt_all, bias_all, inter0);
  gemm_kernel<false, true><<<dim3(2, 128), 256, 0, stream>>>(
      inter0, Bt_all + 262144, bias_all + 256, inter1, 1024, 6, 3, 0);
  gemm_kernel<false, true><<<dim3(2, 32), 256, 0, stream>>>(
      inter1, Bt_all + 2 * 262144, bias_all + 512, inter2, 1024, 4, 2, 0);
  gemm_kernel<false, true><<<dim3(2, 8), 256, 0, stream>>>(
      inter2, Bt_all + 3 * 262144, bias_all + 768, inter3, 1024, 2, 1, 0);
  gemm_kernel<false, true><<<dim3(2, 2), 256, 0, stream>>>(
      inter3, Bt_all + 4 * 262144, bias_all + 1024, inter4, 1024, 0, 0, 1);
  gemm_kernel<true, false><<<dim3(2, 2), 256, 0, stream>>>(
      inter4, Bt_fuse, fuse_b, hbuf, 256, 0, 0, 1);
  fft_gate_kernel<<<8, 256, 0, stream>>>(hbuf, w_gate, wts);
  finalize_kernel<<<1, 64, 0, stream>>>(wts, (float*)d_out);
}